// Round 2
// baseline (1863.490 us; speedup 1.0000x reference)
//
#include <hip/hip_runtime.h>
#include <hip/hip_bf16.h>

typedef unsigned int u32;
typedef _Float16     f16;
typedef f16   h2_t   __attribute__((ext_vector_type(2)));
typedef f16   f16x8v __attribute__((ext_vector_type(8)));
typedef float f32x4  __attribute__((ext_vector_type(4)));

// Problem dims (all inputs/outputs are float32 per the reference)
#define BATCH 128
#define SLEN  512
#define IDIM  256
#define HDIM  256
// ws layout: gx f16 [65536][1024] then wo4 int4 [32][256]
#define GX_BYTES ((size_t)65536 * 1024 * 2)

__device__ __forceinline__ float sigm(float x) {
    return __builtin_amdgcn_rcpf(1.0f + __expf(-x));
}
__device__ __forceinline__ float tanh_f(float x) {
    return 1.0f - 2.0f * __builtin_amdgcn_rcpf(__expf(2.0f * x) + 1.0f);
}
__device__ __forceinline__ f16x8v pack8(float4 a, float4 b) {
    f16x8v v;
    v[0] = (f16)a.x; v[1] = (f16)a.y; v[2] = (f16)a.z; v[3] = (f16)a.w;
    v[4] = (f16)b.x; v[5] = (f16)b.y; v[6] = (f16)b.z; v[7] = (f16)b.w;
    return v;
}

// ---------------------------------------------------------------------------
// Kernel 1: repack Wo h-part (f32 [256 rows][cols 256..511]) -> f16 pairs.
// wo4[j4*256 + u] = int4 of 4 f16x2 pairs covering k = j4*8 .. j4*8+7 of row u.
// Streaming loads in the recurrence then become fully coalesced dwordx4.
// ---------------------------------------------------------------------------
__global__ __launch_bounds__(256) void prep_wo(const float* __restrict__ Wo,
                                               int4* __restrict__ wo4) {
    const int t  = blockIdx.x * 256 + threadIdx.x;  // 0..8191
    const int u  = t >> 5;
    const int j4 = t & 31;
    const float4* p = (const float4*)(Wo + (size_t)u * 512 + 256 + j4 * 8);
    float4 a = p[0], b = p[1];
    h2_t p0 = {(f16)a.x, (f16)a.y}, p1 = {(f16)a.z, (f16)a.w};
    h2_t p2 = {(f16)b.x, (f16)b.y}, p3 = {(f16)b.z, (f16)b.w};
    int4 o;
    o.x = __builtin_bit_cast(int, p0);
    o.y = __builtin_bit_cast(int, p1);
    o.z = __builtin_bit_cast(int, p2);
    o.w = __builtin_bit_cast(int, p3);
    wo4[j4 * 256 + u] = o;
}

// ---------------------------------------------------------------------------
// Kernel 2: gates_x = x @ Wg[:, :256]^T + bg  -> f16 [65536][1024]
// MFMA 16x16x32 f16, 128x128 tile, BK=32, f32->f16 convert during staging,
// LDS padded (stride 40 f16) for conflict-free ds_read_b128 fragment loads.
// grid (512, 8): blockIdx.x = M tile, blockIdx.y = gate-half tile.
// ---------------------------------------------------------------------------
__global__ __launch_bounds__(256) void gemm_gx(
    const float* __restrict__ X,
    const float* __restrict__ Wf, const float* __restrict__ Wi,
    const float* __restrict__ Wc, const float* __restrict__ Wo,
    const float* __restrict__ bf_, const float* __restrict__ bi_,
    const float* __restrict__ bc_, const float* __restrict__ bo_,
    f16* __restrict__ gx) {
    __shared__ _Float16 As[128 * 40];
    __shared__ _Float16 Bs[128 * 40];
    __shared__ float bias_lds[128];

    const int tid = threadIdx.x;
    const int wgy = blockIdx.y;
    const size_t m0 = (size_t)blockIdx.x * 128;

    const float* Wsel[4] = {Wf, Wi, Wc, Wo};
    const float* bsel[4] = {bf_, bi_, bc_, bo_};
    const float* Wseg = Wsel[wgy >> 1];
    const int row_off = (wgy & 1) * 128;

    if (tid < 128) bias_lds[tid] = bsel[wgy >> 1][row_off + tid];

    const int r  = tid >> 2;        // 0..63
    const int c8 = (tid & 3) * 8;   // 0,8,16,24

    const float* Ap0 = X + (m0 + r) * 256 + c8;
    const float* Ap1 = Ap0 + 64 * 256;
    const float* Bp0 = Wseg + (size_t)(row_off + r) * 512 + c8;
    const float* Bp1 = Bp0 + 64 * 512;

    const int lane = tid & 63;
    const int w    = tid >> 6;
    const int wm = w >> 1, wn = w & 1;
    const int col = lane & 15, quad = lane >> 4;

    f32x4 acc[4][4] = {};

    for (int kc = 0; kc < 8; kc++) {
        const int kk = kc * 32;
        float4 a00 = *(const float4*)(Ap0 + kk);
        float4 a01 = *(const float4*)(Ap0 + kk + 4);
        float4 a10 = *(const float4*)(Ap1 + kk);
        float4 a11 = *(const float4*)(Ap1 + kk + 4);
        float4 b00 = *(const float4*)(Bp0 + kk);
        float4 b01 = *(const float4*)(Bp0 + kk + 4);
        float4 b10 = *(const float4*)(Bp1 + kk);
        float4 b11 = *(const float4*)(Bp1 + kk + 4);
        __syncthreads();
        *(f16x8v*)&As[r * 40 + c8]        = pack8(a00, a01);
        *(f16x8v*)&As[(r + 64) * 40 + c8] = pack8(a10, a11);
        *(f16x8v*)&Bs[r * 40 + c8]        = pack8(b00, b01);
        *(f16x8v*)&Bs[(r + 64) * 40 + c8] = pack8(b10, b11);
        __syncthreads();
        f16x8v a[4], b[4];
        #pragma unroll
        for (int i = 0; i < 4; i++)
            a[i] = *(const f16x8v*)&As[(wm * 64 + i * 16 + col) * 40 + quad * 8];
        #pragma unroll
        for (int j = 0; j < 4; j++)
            b[j] = *(const f16x8v*)&Bs[(wn * 64 + j * 16 + col) * 40 + quad * 8];
        #pragma unroll
        for (int i = 0; i < 4; i++)
            #pragma unroll
            for (int j = 0; j < 4; j++)
                acc[i][j] = __builtin_amdgcn_mfma_f32_16x16x32_f16(a[i], b[j], acc[i][j], 0, 0, 0);
    }

    #pragma unroll
    for (int i = 0; i < 4; i++) {
        #pragma unroll
        for (int j = 0; j < 4; j++) {
            #pragma unroll
            for (int rg = 0; rg < 4; rg++) {
                const size_t m = m0 + wm * 64 + i * 16 + quad * 4 + rg;
                const int nl = wn * 64 + j * 16 + col;
                gx[m * 1024 + (size_t)wgy * 128 + nl] = (f16)(acc[i][j][rg] + bias_lds[nl]);
            }
        }
    }
}

// ---------------------------------------------------------------------------
// Kernel 3: the recurrence. 128 WGs (one per batch element) x 256 threads
// (one per hidden unit). f/i/c h-weights register-resident as f16x2
// (384 VGPRs), o-weights streamed coalesced from L2, h in LDS as f16
// (broadcast reads -> conflict-free), c in an fp32 register.
// v_dot2_f32_f16 inner product, fp32 accumulate.
// Epilogue: out = h_final @ Wout^T + bout (fp32).
// ---------------------------------------------------------------------------
__global__ __launch_bounds__(256, 1) void lstm_rec(
    const float* __restrict__ Wf, const float* __restrict__ Wi, const float* __restrict__ Wc,
    const f16* __restrict__ gx, const int4* __restrict__ wo4,
    const float* __restrict__ Wout, const float* __restrict__ bout,
    float* __restrict__ out) {
    __shared__ _Float16 h16[256] __attribute__((aligned(16)));
    const int b = blockIdx.x, u = threadIdx.x;

    h2_t wf2[128], wi2[128], wc2[128];
    {
        const float4* pf = (const float4*)(Wf + (size_t)u * 512 + 256);
        const float4* pi = (const float4*)(Wi + (size_t)u * 512 + 256);
        const float4* pc = (const float4*)(Wc + (size_t)u * 512 + 256);
        #pragma unroll
        for (int q = 0; q < 64; q++) {
            float4 v = pf[q];
            wf2[q*2+0] = h2_t{(f16)v.x, (f16)v.y};
            wf2[q*2+1] = h2_t{(f16)v.z, (f16)v.w};
        }
        #pragma unroll
        for (int q = 0; q < 64; q++) {
            float4 v = pi[q];
            wi2[q*2+0] = h2_t{(f16)v.x, (f16)v.y};
            wi2[q*2+1] = h2_t{(f16)v.z, (f16)v.w};
        }
        #pragma unroll
        for (int q = 0; q < 64; q++) {
            float4 v = pc[q];
            wc2[q*2+0] = h2_t{(f16)v.x, (f16)v.y};
            wc2[q*2+1] = h2_t{(f16)v.z, (f16)v.w};
        }
    }

    float c = 0.0f;
    h16[u] = (f16)0.0f;
    __syncthreads();

    const f16*  g   = gx  + (size_t)b * 512 * 1024 + u;
    const int4* wop = wo4 + u;

    // prefetch step 0's x-gates
    float nf = (float)g[0];
    float ni = (float)g[256];
    float ng = (float)g[512];
    float no = (float)g[768];

    for (int t = 0; t < 512; t++) {
        float af = nf, ai = ni, ag = ng, ao = no;
        g += 1024;
        if (t != 511) {                 // uniform branch, prefetch next step
            nf = (float)g[0];
            ni = (float)g[256];
            ng = (float)g[512];
            no = (float)g[768];
        }
        const int4* hv = (const int4*)h16;
        #pragma unroll
        for (int j4 = 0; j4 < 32; j4++) {
            int4 hp = hv[j4];           // broadcast: all lanes same address
            int4 wo = wop[j4 * 256];    // coalesced L2 stream
            h2_t h0 = __builtin_bit_cast(h2_t, hp.x);
            h2_t h1 = __builtin_bit_cast(h2_t, hp.y);
            h2_t h2 = __builtin_bit_cast(h2_t, hp.z);
            h2_t h3 = __builtin_bit_cast(h2_t, hp.w);
            // interleave accumulators: dep distance 4 hides VALU latency
            af = __builtin_amdgcn_fdot2(wf2[j4*4+0], h0, af, false);
            ai = __builtin_amdgcn_fdot2(wi2[j4*4+0], h0, ai, false);
            ag = __builtin_amdgcn_fdot2(wc2[j4*4+0], h0, ag, false);
            ao = __builtin_amdgcn_fdot2(__builtin_bit_cast(h2_t, wo.x), h0, ao, false);
            af = __builtin_amdgcn_fdot2(wf2[j4*4+1], h1, af, false);
            ai = __builtin_amdgcn_fdot2(wi2[j4*4+1], h1, ai, false);
            ag = __builtin_amdgcn_fdot2(wc2[j4*4+1], h1, ag, false);
            ao = __builtin_amdgcn_fdot2(__builtin_bit_cast(h2_t, wo.y), h1, ao, false);
            af = __builtin_amdgcn_fdot2(wf2[j4*4+2], h2, af, false);
            ai = __builtin_amdgcn_fdot2(wi2[j4*4+2], h2, ai, false);
            ag = __builtin_amdgcn_fdot2(wc2[j4*4+2], h2, ag, false);
            ao = __builtin_amdgcn_fdot2(__builtin_bit_cast(h2_t, wo.z), h2, ao, false);
            af = __builtin_amdgcn_fdot2(wf2[j4*4+3], h3, af, false);
            ai = __builtin_amdgcn_fdot2(wi2[j4*4+3], h3, ai, false);
            ag = __builtin_amdgcn_fdot2(wc2[j4*4+3], h3, ag, false);
            ao = __builtin_amdgcn_fdot2(__builtin_bit_cast(h2_t, wo.w), h3, ao, false);
        }
        float sf = sigm(af), si = sigm(ai), so = sigm(ao);
        float tg = tanh_f(ag);
        c = c * sf + si * tg;
        float h = tanh_f(c) * so;
        __syncthreads();          // everyone done reading old h
        h16[u] = (f16)h;
        __syncthreads();          // new h visible
    }

    // out[b, :] = h_final @ Wout^T + bout   (fp32 output)
    if (u < 128) {
        float acc = bout[u];
        const float4* wv = (const float4*)(Wout + (size_t)u * 256);
        #pragma unroll
        for (int q = 0; q < 64; q++) {
            float4 v = wv[q];
            acc += v.x * (float)h16[q*4+0];
            acc += v.y * (float)h16[q*4+1];
            acc += v.z * (float)h16[q*4+2];
            acc += v.w * (float)h16[q*4+3];
        }
        out[b * 128 + u] = acc;
    }
}

extern "C" void kernel_launch(void* const* d_in, const int* in_sizes, int n_in,
                              void* d_out, int out_size, void* d_ws, size_t ws_size,
                              hipStream_t stream) {
    const float* x    = (const float*)d_in[0];
    const float* Wf   = (const float*)d_in[1];
    const float* bfv  = (const float*)d_in[2];
    const float* Wi   = (const float*)d_in[3];
    const float* biv  = (const float*)d_in[4];
    const float* Wc   = (const float*)d_in[5];
    const float* bcv  = (const float*)d_in[6];
    const float* Wo   = (const float*)d_in[7];
    const float* bov  = (const float*)d_in[8];
    const float* Wout = (const float*)d_in[9];
    const float* bout = (const float*)d_in[10];

    f16*  gx  = (f16*)d_ws;
    int4* wo4 = (int4*)((char*)d_ws + GX_BYTES);

    prep_wo<<<32, 256, 0, stream>>>(Wo, wo4);
    gemm_gx<<<dim3(512, 8), 256, 0, stream>>>(x, Wf, Wi, Wc, Wo, bfv, biv, bcv, bov, gx);
    lstm_rec<<<128, 256, 0, stream>>>(Wf, Wi, Wc, gx, wo4, Wout, bout, (float*)d_out);
}

// Round 4
// 1710.273 us; speedup vs baseline: 1.0896x; 1.0896x over previous
//
#include <hip/hip_runtime.h>
#include <hip/hip_bf16.h>

typedef unsigned int u32;
typedef _Float16     f16;
typedef f16   h2_t   __attribute__((ext_vector_type(2)));
typedef f16   f16x8v __attribute__((ext_vector_type(8)));
typedef float f32x4  __attribute__((ext_vector_type(4)));

// Problem dims (all inputs/outputs are float32 per the reference)
#define BATCH 128
#define SLEN  512
#define IDIM  256
#define HDIM  256
// ws layout: gx f16 [65536][1024] then wo4 int4 [16][512]
#define GX_BYTES ((size_t)65536 * 1024 * 2)

__device__ __forceinline__ float sigm(float x) {
    return __builtin_amdgcn_rcpf(1.0f + __expf(-x));
}
__device__ __forceinline__ float tanh_f(float x) {
    return 1.0f - 2.0f * __builtin_amdgcn_rcpf(__expf(2.0f * x) + 1.0f);
}
__device__ __forceinline__ f16x8v pack8(float4 a, float4 b) {
    f16x8v v;
    v[0] = (f16)a.x; v[1] = (f16)a.y; v[2] = (f16)a.z; v[3] = (f16)a.w;
    v[4] = (f16)b.x; v[5] = (f16)b.y; v[6] = (f16)b.z; v[7] = (f16)b.w;
    return v;
}

// ---------------------------------------------------------------------------
// Kernel 1: repack Wo h-part (f32 [256 rows][cols 256..511]) -> f16 pairs.
// Layout matches lstm_rec's thread map (u = tid>>1, half = tid&1):
//   wo4[j*512 + u*2 + half] = int4 of 4 f16x2 covering k = half*128 + j*8
// so each step's load j is one fully-coalesced dwordx4 per wave.
// ---------------------------------------------------------------------------
__global__ __launch_bounds__(256) void prep_wo(const float* __restrict__ Wo,
                                               int4* __restrict__ wo4) {
    const int t    = blockIdx.x * 256 + threadIdx.x;  // 0..8191
    const int j    = t >> 9;        // 0..15
    const int r    = t & 511;
    const int u    = r >> 1;
    const int half = r & 1;
    const float4* p = (const float4*)(Wo + (size_t)u * 512 + 256 + half * 128 + j * 8);
    float4 a = p[0], b = p[1];
    h2_t p0 = {(f16)a.x, (f16)a.y}, p1 = {(f16)a.z, (f16)a.w};
    h2_t p2 = {(f16)b.x, (f16)b.y}, p3 = {(f16)b.z, (f16)b.w};
    int4 o;
    o.x = __builtin_bit_cast(int, p0);
    o.y = __builtin_bit_cast(int, p1);
    o.z = __builtin_bit_cast(int, p2);
    o.w = __builtin_bit_cast(int, p3);
    wo4[t] = o;
}

// ---------------------------------------------------------------------------
// Kernel 2: gates_x = x @ Wg[:, :256]^T + bg  -> f16 [65536][1024]
// MFMA 16x16x32 f16, 128x128 tile, BK=32, f32->f16 convert during staging,
// LDS padded (stride 40 f16) for conflict-free ds_read_b128 fragment loads.
// ---------------------------------------------------------------------------
__global__ __launch_bounds__(256) void gemm_gx(
    const float* __restrict__ X,
    const float* __restrict__ Wf, const float* __restrict__ Wi,
    const float* __restrict__ Wc, const float* __restrict__ Wo,
    const float* __restrict__ bf_, const float* __restrict__ bi_,
    const float* __restrict__ bc_, const float* __restrict__ bo_,
    f16* __restrict__ gx) {
    __shared__ _Float16 As[128 * 40];
    __shared__ _Float16 Bs[128 * 40];
    __shared__ float bias_lds[128];

    const int tid = threadIdx.x;
    const int wgy = blockIdx.y;
    const size_t m0 = (size_t)blockIdx.x * 128;

    const float* Wsel[4] = {Wf, Wi, Wc, Wo};
    const float* bsel[4] = {bf_, bi_, bc_, bo_};
    const float* Wseg = Wsel[wgy >> 1];
    const int row_off = (wgy & 1) * 128;

    if (tid < 128) bias_lds[tid] = bsel[wgy >> 1][row_off + tid];

    const int r  = tid >> 2;        // 0..63
    const int c8 = (tid & 3) * 8;   // 0,8,16,24

    const float* Ap0 = X + (m0 + r) * 256 + c8;
    const float* Ap1 = Ap0 + 64 * 256;
    const float* Bp0 = Wseg + (size_t)(row_off + r) * 512 + c8;
    const float* Bp1 = Bp0 + 64 * 512;

    const int lane = tid & 63;
    const int w    = tid >> 6;
    const int wm = w >> 1, wn = w & 1;
    const int col = lane & 15, quad = lane >> 4;

    f32x4 acc[4][4] = {};

    for (int kc = 0; kc < 8; kc++) {
        const int kk = kc * 32;
        float4 a00 = *(const float4*)(Ap0 + kk);
        float4 a01 = *(const float4*)(Ap0 + kk + 4);
        float4 a10 = *(const float4*)(Ap1 + kk);
        float4 a11 = *(const float4*)(Ap1 + kk + 4);
        float4 b00 = *(const float4*)(Bp0 + kk);
        float4 b01 = *(const float4*)(Bp0 + kk + 4);
        float4 b10 = *(const float4*)(Bp1 + kk);
        float4 b11 = *(const float4*)(Bp1 + kk + 4);
        __syncthreads();
        *(f16x8v*)&As[r * 40 + c8]        = pack8(a00, a01);
        *(f16x8v*)&As[(r + 64) * 40 + c8] = pack8(a10, a11);
        *(f16x8v*)&Bs[r * 40 + c8]        = pack8(b00, b01);
        *(f16x8v*)&Bs[(r + 64) * 40 + c8] = pack8(b10, b11);
        __syncthreads();
        f16x8v a[4], b[4];
        #pragma unroll
        for (int i = 0; i < 4; i++)
            a[i] = *(const f16x8v*)&As[(wm * 64 + i * 16 + col) * 40 + quad * 8];
        #pragma unroll
        for (int j = 0; j < 4; j++)
            b[j] = *(const f16x8v*)&Bs[(wn * 64 + j * 16 + col) * 40 + quad * 8];
        #pragma unroll
        for (int i = 0; i < 4; i++)
            #pragma unroll
            for (int j = 0; j < 4; j++)
                acc[i][j] = __builtin_amdgcn_mfma_f32_16x16x32_f16(a[i], b[j], acc[i][j], 0, 0, 0);
    }

    #pragma unroll
    for (int i = 0; i < 4; i++) {
        #pragma unroll
        for (int j = 0; j < 4; j++) {
            #pragma unroll
            for (int rg = 0; rg < 4; rg++) {
                const size_t m = m0 + wm * 64 + i * 16 + quad * 4 + rg;
                const int nl = wn * 64 + j * 16 + col;
                gx[m * 1024 + (size_t)wgy * 128 + nl] = (f16)(acc[i][j][rg] + bias_lds[nl]);
            }
        }
    }
}

// ---------------------------------------------------------------------------
// Kernel 3: the recurrence. 128 WGs (one per batch) x 512 threads.
// K-split across lane pairs: u = tid>>1 (hidden unit), half = tid&1 (k-half).
// Each thread holds f/i/c weights for its 128-k half = 192 VGPRs — under the
// 256 arch-VGPR limit (round 2 showed 384-live-VGPR designs spill).
// o-weights streamed coalesced from L2; partial sums combined with
// __shfl_xor across the lane pair (same wave, no barrier).
// NOTE (round 3 bug): only half==0 carries the x-gate preactivation —
// initializing both halves with it double-counts after the shuffle-add.
// ---------------------------------------------------------------------------
__global__ __launch_bounds__(512, 2) void lstm_rec(
    const float* __restrict__ Wf, const float* __restrict__ Wi, const float* __restrict__ Wc,
    const f16* __restrict__ gx, const int4* __restrict__ wo4,
    const float* __restrict__ Wout, const float* __restrict__ bout,
    float* __restrict__ out) {
    __shared__ _Float16 h16[256] __attribute__((aligned(16)));
    const int b    = blockIdx.x;
    const int tid  = threadIdx.x;
    const int u    = tid >> 1;
    const int half = tid & 1;
    const int k0   = half * 128;
    const float xsel = half ? 0.0f : 1.0f;   // x-gate term only in half 0

    h2_t wf2[64], wi2[64], wc2[64];
    {
        const float4* pf = (const float4*)(Wf + (size_t)u * 512 + 256 + k0);
        const float4* pi = (const float4*)(Wi + (size_t)u * 512 + 256 + k0);
        const float4* pc = (const float4*)(Wc + (size_t)u * 512 + 256 + k0);
        #pragma unroll
        for (int q = 0; q < 32; q++) {
            float4 v = pf[q];
            wf2[q*2+0] = h2_t{(f16)v.x, (f16)v.y};
            wf2[q*2+1] = h2_t{(f16)v.z, (f16)v.w};
        }
        #pragma unroll
        for (int q = 0; q < 32; q++) {
            float4 v = pi[q];
            wi2[q*2+0] = h2_t{(f16)v.x, (f16)v.y};
            wi2[q*2+1] = h2_t{(f16)v.z, (f16)v.w};
        }
        #pragma unroll
        for (int q = 0; q < 32; q++) {
            float4 v = pc[q];
            wc2[q*2+0] = h2_t{(f16)v.x, (f16)v.y};
            wc2[q*2+1] = h2_t{(f16)v.z, (f16)v.w};
        }
    }

    float c = 0.0f;
    if (tid < 256) h16[tid] = (f16)0.0f;
    __syncthreads();

    const f16*  g   = gx + (size_t)b * 512 * 1024 + u;
    const int4* wop = wo4 + tid;
    const int4* hv  = (const int4*)(h16 + k0);

    // prefetch step 0's x-gates
    float nf = (float)g[0];
    float ni = (float)g[256];
    float ng = (float)g[512];
    float no = (float)g[768];

    for (int t = 0; t < 512; t++) {
        // half 0 carries gate_x; half 1 accumulates from zero (no double count)
        float af = xsel * nf, ai = xsel * ni, ag = xsel * ng, ao = xsel * no;
        g += 1024;
        if (t != 511) {                 // uniform branch, prefetch next step
            nf = (float)g[0];
            ni = (float)g[256];
            ng = (float)g[512];
            no = (float)g[768];
        }
        #pragma unroll
        for (int j4 = 0; j4 < 16; j4++) {
            int4 hp = hv[j4];           // 2 distinct addrs per wave: free
            int4 wo = wop[j4 * 512];    // coalesced L2 stream
            h2_t h0 = __builtin_bit_cast(h2_t, hp.x);
            h2_t h1 = __builtin_bit_cast(h2_t, hp.y);
            h2_t h2 = __builtin_bit_cast(h2_t, hp.z);
            h2_t h3 = __builtin_bit_cast(h2_t, hp.w);
            // interleave accumulators: dep distance 4 hides VALU latency
            af = __builtin_amdgcn_fdot2(wf2[j4*4+0], h0, af, false);
            ai = __builtin_amdgcn_fdot2(wi2[j4*4+0], h0, ai, false);
            ag = __builtin_amdgcn_fdot2(wc2[j4*4+0], h0, ag, false);
            ao = __builtin_amdgcn_fdot2(__builtin_bit_cast(h2_t, wo.x), h0, ao, false);
            af = __builtin_amdgcn_fdot2(wf2[j4*4+1], h1, af, false);
            ai = __builtin_amdgcn_fdot2(wi2[j4*4+1], h1, ai, false);
            ag = __builtin_amdgcn_fdot2(wc2[j4*4+1], h1, ag, false);
            ao = __builtin_amdgcn_fdot2(__builtin_bit_cast(h2_t, wo.y), h1, ao, false);
            af = __builtin_amdgcn_fdot2(wf2[j4*4+2], h2, af, false);
            ai = __builtin_amdgcn_fdot2(wi2[j4*4+2], h2, ai, false);
            ag = __builtin_amdgcn_fdot2(wc2[j4*4+2], h2, ag, false);
            ao = __builtin_amdgcn_fdot2(__builtin_bit_cast(h2_t, wo.z), h2, ao, false);
            af = __builtin_amdgcn_fdot2(wf2[j4*4+3], h3, af, false);
            ai = __builtin_amdgcn_fdot2(wi2[j4*4+3], h3, ai, false);
            ag = __builtin_amdgcn_fdot2(wc2[j4*4+3], h3, ag, false);
            ao = __builtin_amdgcn_fdot2(__builtin_bit_cast(h2_t, wo.w), h3, ao, false);
        }
        // combine K-halves across the lane pair (same wave):
        // lane0 holds gate_x + dot(half0), lane1 holds dot(half1);
        // after the add both lanes hold the identical full preactivation.
        af += __shfl_xor(af, 1);
        ai += __shfl_xor(ai, 1);
        ag += __shfl_xor(ag, 1);
        ao += __shfl_xor(ao, 1);
        float sf = sigm(af), si = sigm(ai), so = sigm(ao);
        float tg = tanh_f(ag);
        c = c * sf + si * tg;
        float h = tanh_f(c) * so;
        __syncthreads();          // everyone done reading old h
        h16[u] = (f16)h;          // pair-lanes store identical value
        __syncthreads();          // new h visible
    }

    // out[b, :] = h_final @ Wout^T + bout   (fp32 output)
    if (tid < 128) {
        float acc = bout[tid];
        const float4* wv = (const float4*)(Wout + (size_t)tid * 256);
        #pragma unroll
        for (int q = 0; q < 64; q++) {
            float4 v = wv[q];
            acc += v.x * (float)h16[q*4+0];
            acc += v.y * (float)h16[q*4+1];
            acc += v.z * (float)h16[q*4+2];
            acc += v.w * (float)h16[q*4+3];
        }
        out[b * 128 + tid] = acc;
    }
}

extern "C" void kernel_launch(void* const* d_in, const int* in_sizes, int n_in,
                              void* d_out, int out_size, void* d_ws, size_t ws_size,
                              hipStream_t stream) {
    const float* x    = (const float*)d_in[0];
    const float* Wf   = (const float*)d_in[1];
    const float* bfv  = (const float*)d_in[2];
    const float* Wi   = (const float*)d_in[3];
    const float* biv  = (const float*)d_in[4];
    const float* Wc   = (const float*)d_in[5];
    const float* bcv  = (const float*)d_in[6];
    const float* Wo   = (const float*)d_in[7];
    const float* bov  = (const float*)d_in[8];
    const float* Wout = (const float*)d_in[9];
    const float* bout = (const float*)d_in[10];

    f16*  gx  = (f16*)d_ws;
    int4* wo4 = (int4*)((char*)d_ws + GX_BYTES);

    prep_wo<<<32, 256, 0, stream>>>(Wo, wo4);
    gemm_gx<<<dim3(512, 8), 256, 0, stream>>>(x, Wf, Wi, Wc, Wo, bfv, biv, bcv, bov, gx);
    lstm_rec<<<128, 512, 0, stream>>>(Wf, Wi, Wc, gx, wo4, Wout, bout, (float*)d_out);
}

// Round 5
// 1353.894 us; speedup vs baseline: 1.3764x; 1.2632x over previous
//
#include <hip/hip_runtime.h>
#include <hip/hip_bf16.h>

typedef unsigned int u32;
typedef _Float16     f16;
typedef f16   f16x8v __attribute__((ext_vector_type(8)));
typedef float f32x4  __attribute__((ext_vector_type(4)));

// Problem dims (all inputs/outputs are float32 per the reference)
#define BATCH 128
#define SLEN  512
#define IDIM  256
#define HDIM  256
#define GX_BYTES ((size_t)65536 * 1024 * 2)
#define OSTRIDE 264   // o-gate LDS row stride in f16 (256 + 8 pad)

__device__ __forceinline__ float sigm(float x) {
    return __builtin_amdgcn_rcpf(1.0f + __expf(-x));
}
__device__ __forceinline__ float tanh_f(float x) {
    return 1.0f - 2.0f * __builtin_amdgcn_rcpf(__expf(2.0f * x) + 1.0f);
}
__device__ __forceinline__ f16x8v pack8(float4 a, float4 b) {
    f16x8v v;
    v[0] = (f16)a.x; v[1] = (f16)a.y; v[2] = (f16)a.z; v[3] = (f16)a.w;
    v[4] = (f16)b.x; v[5] = (f16)b.y; v[6] = (f16)b.z; v[7] = (f16)b.w;
    return v;
}
__device__ __forceinline__ float sel4(int q, float a, float b, float c, float d) {
    return q == 0 ? a : (q == 1 ? b : (q == 2 ? c : d));
}

// ---------------------------------------------------------------------------
// Kernel 1: gates_x = x @ Wg[:, :256]^T + bg  -> f16 [65536][1024]
// MFMA 16x16x32 f16, 128x128 tile, BK=32 (unchanged from round 2, passing).
// ---------------------------------------------------------------------------
__global__ __launch_bounds__(256) void gemm_gx(
    const float* __restrict__ X,
    const float* __restrict__ Wf, const float* __restrict__ Wi,
    const float* __restrict__ Wc, const float* __restrict__ Wo,
    const float* __restrict__ bf_, const float* __restrict__ bi_,
    const float* __restrict__ bc_, const float* __restrict__ bo_,
    f16* __restrict__ gx) {
    __shared__ _Float16 As[128 * 40];
    __shared__ _Float16 Bs[128 * 40];
    __shared__ float bias_lds[128];

    const int tid = threadIdx.x;
    const int wgy = blockIdx.y;
    const size_t m0 = (size_t)blockIdx.x * 128;

    const float* Wsel[4] = {Wf, Wi, Wc, Wo};
    const float* bsel[4] = {bf_, bi_, bc_, bo_};
    const float* Wseg = Wsel[wgy >> 1];
    const int row_off = (wgy & 1) * 128;

    if (tid < 128) bias_lds[tid] = bsel[wgy >> 1][row_off + tid];

    const int r  = tid >> 2;
    const int c8 = (tid & 3) * 8;

    const float* Ap0 = X + (m0 + r) * 256 + c8;
    const float* Ap1 = Ap0 + 64 * 256;
    const float* Bp0 = Wseg + (size_t)(row_off + r) * 512 + c8;
    const float* Bp1 = Bp0 + 64 * 512;

    const int lane = tid & 63;
    const int w    = tid >> 6;
    const int wm = w >> 1, wn = w & 1;
    const int col = lane & 15, quad = lane >> 4;

    f32x4 acc[4][4] = {};

    for (int kc = 0; kc < 8; kc++) {
        const int kk = kc * 32;
        float4 a00 = *(const float4*)(Ap0 + kk);
        float4 a01 = *(const float4*)(Ap0 + kk + 4);
        float4 a10 = *(const float4*)(Ap1 + kk);
        float4 a11 = *(const float4*)(Ap1 + kk + 4);
        float4 b00 = *(const float4*)(Bp0 + kk);
        float4 b01 = *(const float4*)(Bp0 + kk + 4);
        float4 b10 = *(const float4*)(Bp1 + kk);
        float4 b11 = *(const float4*)(Bp1 + kk + 4);
        __syncthreads();
        *(f16x8v*)&As[r * 40 + c8]        = pack8(a00, a01);
        *(f16x8v*)&As[(r + 64) * 40 + c8] = pack8(a10, a11);
        *(f16x8v*)&Bs[r * 40 + c8]        = pack8(b00, b01);
        *(f16x8v*)&Bs[(r + 64) * 40 + c8] = pack8(b10, b11);
        __syncthreads();
        f16x8v a[4], b[4];
        #pragma unroll
        for (int i = 0; i < 4; i++)
            a[i] = *(const f16x8v*)&As[(wm * 64 + i * 16 + col) * 40 + quad * 8];
        #pragma unroll
        for (int j = 0; j < 4; j++)
            b[j] = *(const f16x8v*)&Bs[(wn * 64 + j * 16 + col) * 40 + quad * 8];
        #pragma unroll
        for (int i = 0; i < 4; i++)
            #pragma unroll
            for (int j = 0; j < 4; j++)
                acc[i][j] = __builtin_amdgcn_mfma_f32_16x16x32_f16(a[i], b[j], acc[i][j], 0, 0, 0);
    }

    #pragma unroll
    for (int i = 0; i < 4; i++) {
        #pragma unroll
        for (int j = 0; j < 4; j++) {
            #pragma unroll
            for (int rg = 0; rg < 4; rg++) {
                const size_t m = m0 + wm * 64 + i * 16 + quad * 4 + rg;
                const int nl = wn * 64 + j * 16 + col;
                gx[m * 1024 + (size_t)wgy * 128 + nl] = (f16)(acc[i][j][rg] + bias_lds[nl]);
            }
        }
    }
}

// ---------------------------------------------------------------------------
// Kernel 2: the recurrence, MFMA formulation.
// 128 WGs (one per batch) x 256 threads (4 waves, 1 wave/SIMD, 512-reg budget).
// Wave w owns units [64w, 64w+64). N-slice layout per wave (16 MFMA N-tiles):
//   tiles 0-3 = f, 4-7 = i, 8-11 = c (B-frags register/AGPR-resident, 384 regs),
//   tiles 12-15 = o (B-frags re-read each step from LDS, 135 KB, stride 264).
// A-operand = h broadcast (replicated across M rows); D rows identical, so
// lane l extracts unit u = 64w + l's gates via cndmask selects on quad.
// ---------------------------------------------------------------------------
__global__ __launch_bounds__(256, 1) void lstm_rec(
    const float* __restrict__ Wf, const float* __restrict__ Wi,
    const float* __restrict__ Wc, const float* __restrict__ Wo,
    const f16* __restrict__ gx,
    const float* __restrict__ Wout, const float* __restrict__ bout,
    float* __restrict__ out) {
    __shared__ _Float16 oL[256 * OSTRIDE];           // 135168 B
    __shared__ _Float16 h16[256] __attribute__((aligned(16)));

    const int tid  = threadIdx.x;
    const int b    = blockIdx.x;
    const int w    = tid >> 6;
    const int l    = tid & 63;
    const int l15  = l & 15;
    const int quad = l >> 4;

    // --- stage o-gate h-weights into LDS (row u = tid, f32 -> f16) ---
    {
        const float4* src = (const float4*)(Wo + (size_t)tid * 512 + 256);
        _Float16* dst = &oL[tid * OSTRIDE];
        #pragma unroll
        for (int kq = 0; kq < 32; kq++) {
            float4 a = src[kq * 2], bb = src[kq * 2 + 1];
            *(f16x8v*)&dst[kq * 8] = pack8(a, bb);
        }
    }

    // --- f/i/c h-weights -> MFMA B-fragments (384 regs; MFMA-only use) ---
    f16x8v wB[12][8];
    {
        const float* gp[3] = {Wf, Wi, Wc};
        #pragma unroll
        for (int g = 0; g < 3; g++) {
            #pragma unroll
            for (int a = 0; a < 4; a++) {
                const int u = 64 * w + 16 * a + l15;
                const float* row = gp[g] + (size_t)u * 512 + 256 + quad * 8;
                #pragma unroll
                for (int kt = 0; kt < 8; kt++) {
                    float4 x0 = *(const float4*)(row + kt * 32);
                    float4 x1 = *(const float4*)(row + kt * 32 + 4);
                    wB[g * 4 + a][kt] = pack8(x0, x1);
                }
            }
        }
    }

    float c = 0.0f;
    h16[tid] = (f16)0.0f;
    __syncthreads();

    const _Float16* hA = &h16[quad * 8];                       // + kt*32
    const _Float16* oR = &oL[(64 * w + l15) * OSTRIDE + quad * 8]; // + a*16*OSTRIDE + kt*32
    const f16* gxr = gx + (size_t)b * 512 * 1024 + tid;

    // gx prefetch for t=0
    float pf = (float)gxr[0];
    float pi_ = (float)gxr[256];
    float pg = (float)gxr[512];
    float po = (float)gxr[768];

    for (int t = 0; t < 512; t++) {
        // current step's x-gate preactivations; prefetch next step's early
        float gf = pf, gi = pi_, gg = pg, go = po;
        if (t != 511) {
            const f16* gn = gxr + (size_t)(t + 1) * 1024;
            pf  = (float)gn[0];
            pi_ = (float)gn[256];
            pg  = (float)gn[512];
            po  = (float)gn[768];
        }

        f32x4 acc[16];
        #pragma unroll
        for (int i = 0; i < 16; i++) acc[i] = f32x4{0.f, 0.f, 0.f, 0.f};

        // rolling A / o-fragment loads (depth-1 prefetch inside the kt loop)
        f16x8v A0 = *(const f16x8v*)&hA[0];
        f16x8v o0[4], o1[4];
        f16x8v A1 = A0;
        #pragma unroll
        for (int a = 0; a < 4; a++)
            o0[a] = *(const f16x8v*)&oR[a * 16 * OSTRIDE];

        #pragma unroll
        for (int kt = 0; kt < 8; kt++) {
            if (kt < 7) {
                A1 = *(const f16x8v*)&hA[(kt + 1) * 32];
                #pragma unroll
                for (int a = 0; a < 4; a++)
                    o1[a] = *(const f16x8v*)&oR[a * 16 * OSTRIDE + (kt + 1) * 32];
            }
            #pragma unroll
            for (int tt = 0; tt < 12; tt++)
                acc[tt] = __builtin_amdgcn_mfma_f32_16x16x32_f16(A0, wB[tt][kt], acc[tt], 0, 0, 0);
            #pragma unroll
            for (int a = 0; a < 4; a++)
                acc[12 + a] = __builtin_amdgcn_mfma_f32_16x16x32_f16(A0, o0[a], acc[12 + a], 0, 0, 0);
            A0 = A1;
            o0[0] = o1[0]; o0[1] = o1[1]; o0[2] = o1[2]; o0[3] = o1[3];
        }

        // extract this lane's unit (u = tid): gate tile = quad, reg 0 (rows replicated)
        float df = sel4(quad, acc[0][0],  acc[1][0],  acc[2][0],  acc[3][0]);
        float di = sel4(quad, acc[4][0],  acc[5][0],  acc[6][0],  acc[7][0]);
        float dg = sel4(quad, acc[8][0],  acc[9][0],  acc[10][0], acc[11][0]);
        float dd = sel4(quad, acc[12][0], acc[13][0], acc[14][0], acc[15][0]);

        float F = gf + df, I = gi + di, G = gg + dg, O = go + dd;
        float sf = sigm(F), si = sigm(I), so = sigm(O);
        float tg = tanh_f(G);
        c = c * sf + si * tg;
        float h = tanh_f(c) * so;

        __syncthreads();          // all waves done reading h_{t-1}
        h16[tid] = (f16)h;
        __syncthreads();          // h_t visible
    }

    // out[b, :] = h_final @ Wout^T + bout   (fp32 output)
    if (tid < 128) {
        float acc = bout[tid];
        const float4* wv = (const float4*)(Wout + (size_t)tid * 256);
        #pragma unroll
        for (int q = 0; q < 64; q++) {
            float4 v = wv[q];
            acc += v.x * (float)h16[q * 4 + 0];
            acc += v.y * (float)h16[q * 4 + 1];
            acc += v.z * (float)h16[q * 4 + 2];
            acc += v.w * (float)h16[q * 4 + 3];
        }
        out[b * 128 + tid] = acc;
    }
}

extern "C" void kernel_launch(void* const* d_in, const int* in_sizes, int n_in,
                              void* d_out, int out_size, void* d_ws, size_t ws_size,
                              hipStream_t stream) {
    const float* x    = (const float*)d_in[0];
    const float* Wf   = (const float*)d_in[1];
    const float* bfv  = (const float*)d_in[2];
    const float* Wi   = (const float*)d_in[3];
    const float* biv  = (const float*)d_in[4];
    const float* Wc   = (const float*)d_in[5];
    const float* bcv  = (const float*)d_in[6];
    const float* Wo   = (const float*)d_in[7];
    const float* bov  = (const float*)d_in[8];
    const float* Wout = (const float*)d_in[9];
    const float* bout = (const float*)d_in[10];

    f16* gx = (f16*)d_ws;

    gemm_gx<<<dim3(512, 8), 256, 0, stream>>>(x, Wf, Wi, Wc, Wo, bfv, biv, bcv, bov, gx);
    lstm_rec<<<128, 256, 0, stream>>>(Wf, Wi, Wc, Wo, gx, Wout, bout, (float*)d_out);
}

// Round 6
// 1346.353 us; speedup vs baseline: 1.3841x; 1.0056x over previous
//
#include <hip/hip_runtime.h>
#include <hip/hip_bf16.h>

typedef unsigned int u32;
typedef _Float16     f16;
typedef f16   f16x8v __attribute__((ext_vector_type(8)));
typedef float f32x4  __attribute__((ext_vector_type(4)));

// Problem dims (all inputs/outputs are float32 per the reference)
#define BATCH 128
#define SLEN  512
#define IDIM  256
#define HDIM  256
#define GX_BYTES ((size_t)65536 * 1024 * 2)

__device__ __forceinline__ float sigm(float x) {
    return __builtin_amdgcn_rcpf(1.0f + __expf(-x));
}
__device__ __forceinline__ float tanh_f(float x) {
    return 1.0f - 2.0f * __builtin_amdgcn_rcpf(__expf(2.0f * x) + 1.0f);
}
__device__ __forceinline__ f16x8v pack8(float4 a, float4 b) {
    f16x8v v;
    v[0] = (f16)a.x; v[1] = (f16)a.y; v[2] = (f16)a.z; v[3] = (f16)a.w;
    v[4] = (f16)b.x; v[5] = (f16)b.y; v[6] = (f16)b.z; v[7] = (f16)b.w;
    return v;
}
__device__ __forceinline__ float sel4(int q, float a, float b, float c, float d) {
    return q == 0 ? a : (q == 1 ? b : (q == 2 ? c : d));
}

// ---------------------------------------------------------------------------
// Kernel 1: gates_x = x @ Wg[:, :256]^T + bg  -> f16 [65536][1024]
// MFMA 16x16x32 f16, 128x128 tile, BK=32 (unchanged, passing).
// ---------------------------------------------------------------------------
__global__ __launch_bounds__(256) void gemm_gx(
    const float* __restrict__ X,
    const float* __restrict__ Wf, const float* __restrict__ Wi,
    const float* __restrict__ Wc, const float* __restrict__ Wo,
    const float* __restrict__ bf_, const float* __restrict__ bi_,
    const float* __restrict__ bc_, const float* __restrict__ bo_,
    f16* __restrict__ gx) {
    __shared__ _Float16 As[128 * 40];
    __shared__ _Float16 Bs[128 * 40];
    __shared__ float bias_lds[128];

    const int tid = threadIdx.x;
    const int wgy = blockIdx.y;
    const size_t m0 = (size_t)blockIdx.x * 128;

    const float* Wsel[4] = {Wf, Wi, Wc, Wo};
    const float* bsel[4] = {bf_, bi_, bc_, bo_};
    const float* Wseg = Wsel[wgy >> 1];
    const int row_off = (wgy & 1) * 128;

    if (tid < 128) bias_lds[tid] = bsel[wgy >> 1][row_off + tid];

    const int r  = tid >> 2;
    const int c8 = (tid & 3) * 8;

    const float* Ap0 = X + (m0 + r) * 256 + c8;
    const float* Ap1 = Ap0 + 64 * 256;
    const float* Bp0 = Wseg + (size_t)(row_off + r) * 512 + c8;
    const float* Bp1 = Bp0 + 64 * 512;

    const int lane = tid & 63;
    const int w    = tid >> 6;
    const int wm = w >> 1, wn = w & 1;
    const int col = lane & 15, quad = lane >> 4;

    f32x4 acc[4][4] = {};

    for (int kc = 0; kc < 8; kc++) {
        const int kk = kc * 32;
        float4 a00 = *(const float4*)(Ap0 + kk);
        float4 a01 = *(const float4*)(Ap0 + kk + 4);
        float4 a10 = *(const float4*)(Ap1 + kk);
        float4 a11 = *(const float4*)(Ap1 + kk + 4);
        float4 b00 = *(const float4*)(Bp0 + kk);
        float4 b01 = *(const float4*)(Bp0 + kk + 4);
        float4 b10 = *(const float4*)(Bp1 + kk);
        float4 b11 = *(const float4*)(Bp1 + kk + 4);
        __syncthreads();
        *(f16x8v*)&As[r * 40 + c8]        = pack8(a00, a01);
        *(f16x8v*)&As[(r + 64) * 40 + c8] = pack8(a10, a11);
        *(f16x8v*)&Bs[r * 40 + c8]        = pack8(b00, b01);
        *(f16x8v*)&Bs[(r + 64) * 40 + c8] = pack8(b10, b11);
        __syncthreads();
        f16x8v a[4], b[4];
        #pragma unroll
        for (int i = 0; i < 4; i++)
            a[i] = *(const f16x8v*)&As[(wm * 64 + i * 16 + col) * 40 + quad * 8];
        #pragma unroll
        for (int j = 0; j < 4; j++)
            b[j] = *(const f16x8v*)&Bs[(wn * 64 + j * 16 + col) * 40 + quad * 8];
        #pragma unroll
        for (int i = 0; i < 4; i++)
            #pragma unroll
            for (int j = 0; j < 4; j++)
                acc[i][j] = __builtin_amdgcn_mfma_f32_16x16x32_f16(a[i], b[j], acc[i][j], 0, 0, 0);
    }

    #pragma unroll
    for (int i = 0; i < 4; i++) {
        #pragma unroll
        for (int j = 0; j < 4; j++) {
            #pragma unroll
            for (int rg = 0; rg < 4; rg++) {
                const size_t m = m0 + wm * 64 + i * 16 + quad * 4 + rg;
                const int nl = wn * 64 + j * 16 + col;
                gx[m * 1024 + (size_t)wgy * 128 + nl] = (f16)(acc[i][j][rg] + bias_lds[nl]);
            }
        }
    }
}

// ---------------------------------------------------------------------------
// Kernel 2: the recurrence, MFMA formulation.
// 128 WGs (one per batch) x 256 threads (4 waves, 1 wave/SIMD, 512-reg file).
// Wave w owns units [64w, 64w+64). 16 MFMA N-tiles per wave:
//   0-3 = f, 4-7 = i, 8-11 = c (B-frags AGPR-resident, 384 regs),
//   12-15 = o, re-read each step from LDS in FRAGMENT-ORDER layout:
//   oL4[((w*4+a)*8+kt)*64 + lane] so each wave access is 64 consecutive
//   int4s (1 KB contiguous, conflict-free b128 — round 5's row-major layout
//   was 8-way bank-conflicted, 3.4e7 conflict cycles).
// o-prefetch rotates across the step boundary (static weights): kt=7
// prefetches next step's kt=0 so post-barrier only the h read is exposed.
// ---------------------------------------------------------------------------
__global__ __launch_bounds__(256, 1) void lstm_rec(
    const float* __restrict__ Wf, const float* __restrict__ Wi,
    const float* __restrict__ Wc, const float* __restrict__ Wo,
    const f16* __restrict__ gx,
    const float* __restrict__ Wout, const float* __restrict__ bout,
    float* __restrict__ out) {
    __shared__ int4 oL4[8192];                       // 128 KiB, fragment-order
    __shared__ _Float16 h16[256] __attribute__((aligned(16)));

    const int tid  = threadIdx.x;
    const int b    = blockIdx.x;
    const int w    = tid >> 6;
    const int l    = tid & 63;
    const int l15  = l & 15;
    const int quad = l >> 4;

    // --- stage o-gate h-weights into LDS in fragment order ---
    // thread tid owns Wo row u=tid: frag(w_,a_,kt,lane=q*16+l15_) covers
    // k = kt*32 + q*8 .. +7 of that row.
    {
        const float4* src = (const float4*)(Wo + (size_t)tid * 512 + 256);
        const int w_ = tid >> 6, a_ = (tid >> 4) & 3, l15_ = tid & 15;
        int4* dst = &oL4[(size_t)(w_ * 4 + a_) * 512 + l15_];
        #pragma unroll
        for (int kt = 0; kt < 8; kt++) {
            #pragma unroll
            for (int q = 0; q < 4; q++) {
                float4 x0 = src[kt * 8 + q * 2];
                float4 x1 = src[kt * 8 + q * 2 + 1];
                f16x8v v = pack8(x0, x1);
                dst[kt * 64 + q * 16] = __builtin_bit_cast(int4, v);
            }
        }
    }

    // --- f/i/c h-weights -> MFMA B-fragments (384 regs; MFMA-only use) ---
    f16x8v wB[12][8];
    {
        const float* gp[3] = {Wf, Wi, Wc};
        #pragma unroll
        for (int g = 0; g < 3; g++) {
            #pragma unroll
            for (int a = 0; a < 4; a++) {
                const int u = 64 * w + 16 * a + l15;
                const float* row = gp[g] + (size_t)u * 512 + 256 + quad * 8;
                #pragma unroll
                for (int kt = 0; kt < 8; kt++) {
                    float4 x0 = *(const float4*)(row + kt * 32);
                    float4 x1 = *(const float4*)(row + kt * 32 + 4);
                    wB[g * 4 + a][kt] = pack8(x0, x1);
                }
            }
        }
    }

    float c = 0.0f;
    h16[tid] = (f16)0.0f;
    __syncthreads();

    const _Float16* hA = &h16[quad * 8];             // + kt*32
    const int4* oR = &oL4[(size_t)w * 2048 + l];     // + a*512 + kt*64
    const f16* gxr = gx + (size_t)b * 512 * 1024 + tid;

    // gx prefetch for t=0
    float pf  = (float)gxr[0];
    float pi_ = (float)gxr[256];
    float pg  = (float)gxr[512];
    float po  = (float)gxr[768];

    // o-fragment prefetch for kt=0 (static across steps)
    f16x8v oc[4], on[4];
    #pragma unroll
    for (int a = 0; a < 4; a++)
        oc[a] = __builtin_bit_cast(f16x8v, oR[a * 512]);

    for (int t = 0; t < 512; t++) {
        float gf = pf, gi = pi_, gg = pg, go = po;
        if (t != 511) {
            const f16* gn = gxr + (size_t)(t + 1) * 1024;
            pf  = (float)gn[0];
            pi_ = (float)gn[256];
            pg  = (float)gn[512];
            po  = (float)gn[768];
        }

        f32x4 acc[16];
        #pragma unroll
        for (int i = 0; i < 16; i++) acc[i] = f32x4{0.f, 0.f, 0.f, 0.f};

        f16x8v A0 = *(const f16x8v*)&hA[0];
        f16x8v A1 = A0;

        #pragma unroll
        for (int kt = 0; kt < 8; kt++) {
            const int ktn = (kt + 1) & 7;            // kt=7 wraps: next step's kt=0
            if (kt < 7)
                A1 = *(const f16x8v*)&hA[(kt + 1) * 32];
            #pragma unroll
            for (int a = 0; a < 4; a++)
                on[a] = __builtin_bit_cast(f16x8v, oR[a * 512 + ktn * 64]);
            #pragma unroll
            for (int tt = 0; tt < 12; tt++)
                acc[tt] = __builtin_amdgcn_mfma_f32_16x16x32_f16(A0, wB[tt][kt], acc[tt], 0, 0, 0);
            #pragma unroll
            for (int a = 0; a < 4; a++)
                acc[12 + a] = __builtin_amdgcn_mfma_f32_16x16x32_f16(A0, oc[a], acc[12 + a], 0, 0, 0);
            A0 = A1;
            oc[0] = on[0]; oc[1] = on[1]; oc[2] = on[2]; oc[3] = on[3];
        }

        // extract this lane's unit (u = tid): gate tile = quad, reg 0
        float df = sel4(quad, acc[0][0],  acc[1][0],  acc[2][0],  acc[3][0]);
        float di = sel4(quad, acc[4][0],  acc[5][0],  acc[6][0],  acc[7][0]);
        float dg = sel4(quad, acc[8][0],  acc[9][0],  acc[10][0], acc[11][0]);
        float dd = sel4(quad, acc[12][0], acc[13][0], acc[14][0], acc[15][0]);

        float F = gf + df, I = gi + di, G = gg + dg, O = go + dd;
        float sf = sigm(F), si = sigm(I), so = sigm(O);
        float tg = tanh_f(G);
        c = c * sf + si * tg;
        float h = tanh_f(c) * so;

        __syncthreads();          // all waves done reading h_{t-1}
        h16[tid] = (f16)h;
        __syncthreads();          // h_t visible
    }

    // out[b, :] = h_final @ Wout^T + bout   (fp32 output)
    if (tid < 128) {
        float acc = bout[tid];
        const float4* wv = (const float4*)(Wout + (size_t)tid * 256);
        #pragma unroll
        for (int q = 0; q < 64; q++) {
            float4 v = wv[q];
            acc += v.x * (float)h16[q * 4 + 0];
            acc += v.y * (float)h16[q * 4 + 1];
            acc += v.z * (float)h16[q * 4 + 2];
            acc += v.w * (float)h16[q * 4 + 3];
        }
        out[b * 128 + tid] = acc;
    }
}

extern "C" void kernel_launch(void* const* d_in, const int* in_sizes, int n_in,
                              void* d_out, int out_size, void* d_ws, size_t ws_size,
                              hipStream_t stream) {
    const float* x    = (const float*)d_in[0];
    const float* Wf   = (const float*)d_in[1];
    const float* bfv  = (const float*)d_in[2];
    const float* Wi   = (const float*)d_in[3];
    const float* biv  = (const float*)d_in[4];
    const float* Wc   = (const float*)d_in[5];
    const float* bcv  = (const float*)d_in[6];
    const float* Wo   = (const float*)d_in[7];
    const float* bov  = (const float*)d_in[8];
    const float* Wout = (const float*)d_in[9];
    const float* bout = (const float*)d_in[10];

    f16* gx = (f16*)d_ws;

    gemm_gx<<<dim3(512, 8), 256, 0, stream>>>(x, Wf, Wi, Wc, Wo, bfv, biv, bcv, bov, gx);
    lstm_rec<<<128, 256, 0, stream>>>(Wf, Wi, Wc, Wo, gx, Wout, bout, (float*)d_out);
}